// Round 1
// baseline (262.976 us; speedup 1.0000x reference)
//
#include <hip/hip_runtime.h>

#define DIM 1024
#define HEADS 16
#define HD 64
#define BATCH 2
#define SEQ 2048
#define ROWS (BATCH*SEQ)          // 4096
#define EPS 1e-6f

typedef float f32x4 __attribute__((ext_vector_type(4)));
typedef short s16x8 __attribute__((ext_vector_type(8)));

static __device__ __forceinline__ short f2bf(float f) {
    union { float f; unsigned u; } x; x.f = f;
    unsigned r = x.u + 0x7FFFu + ((x.u >> 16) & 1u);
    return (short)(r >> 16);
}
static __device__ __forceinline__ float bf2f(short s) {
    union { unsigned u; float f; } x; x.u = ((unsigned)(unsigned short)s) << 16;
    return x.f;
}
static __device__ __forceinline__ s16x8 pack8(float4 lo, float4 hi) {
    s16x8 r;
    r[0]=f2bf(lo.x); r[1]=f2bf(lo.y); r[2]=f2bf(lo.z); r[3]=f2bf(lo.w);
    r[4]=f2bf(hi.x); r[5]=f2bf(hi.y); r[6]=f2bf(hi.z); r[7]=f2bf(hi.w);
    return r;
}

// ---------------------------------------------------------------------------
// GEMM: C[M][Ncols] = A[M][K] * W[Ncols][K]^T   (A,W fp32; compute bf16 MFMA)
// MODE 0: epilogue scatters bf16 into q/k/v [B,H,N,D] buffers (QKV gemm)
// MODE 1: epilogue adds bias and writes fp32 to out (proj gemm)
// Tile: BM=128, BN=128, BK=32; 256 threads = 4 waves in 2x2.
// ---------------------------------------------------------------------------
#define BM 128
#define BN 128
#define BK 32
#define LDT 40   // LDS row stride in shorts (80B, 16B-aligned, breaks bank p2)

template<int MODE>
__global__ __launch_bounds__(256) void gemm_kernel(
    const float* __restrict__ A, const float* __restrict__ W,
    const float* __restrict__ bias,
    short* __restrict__ qb, short* __restrict__ kb, short* __restrict__ vb,
    float* __restrict__ out)
{
    alignas(16) __shared__ short As[BM*LDT];
    alignas(16) __shared__ short Bs[BN*LDT];
    const int tid  = threadIdx.x;
    const int lane = tid & 63, wave = tid >> 6;
    const int wr = wave >> 1, wc = wave & 1;
    const int c = lane & 15, g = lane >> 4;
    const int brow = blockIdx.y * BM, bcol = blockIdx.x * BN;
    const int sr = tid >> 1, sk = (tid & 1) * 16;

    f32x4 acc[4][4] = {};

    for (int k0 = 0; k0 < DIM; k0 += BK) {
        const float4* pa = (const float4*)(A + (size_t)(brow + sr) * DIM + k0 + sk);
        const float4* pb = (const float4*)(W + (size_t)(bcol + sr) * DIM + k0 + sk);
        float4 a0 = pa[0], a1 = pa[1], a2 = pa[2], a3 = pa[3];
        float4 b0 = pb[0], b1 = pb[1], b2 = pb[2], b3 = pb[3];
        *(s16x8*)&As[sr*LDT + sk]     = pack8(a0, a1);
        *(s16x8*)&As[sr*LDT + sk + 8] = pack8(a2, a3);
        *(s16x8*)&Bs[sr*LDT + sk]     = pack8(b0, b1);
        *(s16x8*)&Bs[sr*LDT + sk + 8] = pack8(b2, b3);
        __syncthreads();

        s16x8 af[4], bf[4];
        #pragma unroll
        for (int m = 0; m < 4; m++)
            af[m] = *(const s16x8*)&As[(wr*64 + m*16 + c)*LDT + g*8];
        #pragma unroll
        for (int n = 0; n < 4; n++)
            bf[n] = *(const s16x8*)&Bs[(wc*64 + n*16 + c)*LDT + g*8];
        #pragma unroll
        for (int m = 0; m < 4; m++)
            #pragma unroll
            for (int n = 0; n < 4; n++)
                acc[m][n] = __builtin_amdgcn_mfma_f32_16x16x32_bf16(af[m], bf[n], acc[m][n], 0, 0, 0);
        __syncthreads();
    }

    // Epilogue. D layout: col = lane&15, row = (lane>>4)*4 + j   [m89]
    if (MODE == 0) {
        #pragma unroll
        for (int n = 0; n < 4; n++) {
            int col = bcol + wc*64 + n*16 + c;
            int t = col >> 10, h = (col >> 6) & 15, d = col & 63;
            short* dst = (t == 0) ? qb : (t == 1) ? kb : vb;
            #pragma unroll
            for (int m = 0; m < 4; m++) {
                #pragma unroll
                for (int j = 0; j < 4; j++) {
                    int row = brow + wr*64 + m*16 + g*4 + j;
                    int bi = row >> 11, ni = row & (SEQ-1);
                    dst[(((size_t)(bi*HEADS + h))*SEQ + ni)*HD + d] = f2bf(acc[m][n][j]);
                }
            }
        }
    } else {
        #pragma unroll
        for (int n = 0; n < 4; n++) {
            int col = bcol + wc*64 + n*16 + c;
            float bv = bias[col];
            #pragma unroll
            for (int m = 0; m < 4; m++) {
                #pragma unroll
                for (int j = 0; j < 4; j++) {
                    int row = brow + wr*64 + m*16 + g*4 + j;
                    out[(size_t)row*DIM + col] = acc[m][n][j] + bv;
                }
            }
        }
    }
}

// ---------------------------------------------------------------------------
// LayerNorm over head_dim=64 for q and k (in-place on bf16 [B,H,N,D]).
// One wave per row; q gets the D^-0.5 scale folded in.
// ---------------------------------------------------------------------------
__global__ __launch_bounds__(256) void ln_qk(
    short* __restrict__ qb, short* __restrict__ kb,
    const float* __restrict__ qg, const float* __restrict__ qbeta,
    const float* __restrict__ kg, const float* __restrict__ kbeta)
{
    const int gw = blockIdx.x * 4 + (threadIdx.x >> 6);
    const int lane = threadIdx.x & 63;
    const int per = BATCH*HEADS*SEQ;            // rows per tensor
    const int which = gw >= per;                // 0:q 1:k
    const int row = which ? gw - per : gw;
    short* buf = which ? kb : qb;
    const float* gamma = which ? kg : qg;
    const float* beta  = which ? kbeta : qbeta;
    const float scale  = which ? 1.0f : 0.125f; // HD^-0.5

    short* p = buf + (size_t)row * HD;
    float v = bf2f(p[lane]);
    float s = v;
    #pragma unroll
    for (int m = 32; m; m >>= 1) s += __shfl_xor(s, m);
    float mu = s * (1.0f/64.0f);
    float d = v - mu;
    float vs = d * d;
    #pragma unroll
    for (int m = 32; m; m >>= 1) vs += __shfl_xor(vs, m);
    float rstd = rsqrtf(vs * (1.0f/64.0f) + EPS);
    p[lane] = f2bf((d * rstd * gamma[lane] + beta[lane]) * scale);
}

// ---------------------------------------------------------------------------
// Flash attention: one block per (b*h, 64-row q tile); 4 waves x 16 q rows.
// q already scaled by D^-0.5. Writes fp32 [B*N][DIM] (col = h*64+d).
// ---------------------------------------------------------------------------
__global__ __launch_bounds__(256) void attn_kernel(
    const short* __restrict__ qbuf, const short* __restrict__ kbuf,
    const short* __restrict__ vbuf, float* __restrict__ aout)
{
    constexpr int KB_T = 64;
    constexpr int LT = 72;   // LDS stride (144B, 16B-aligned)
    alignas(16) __shared__ short Ks[KB_T*LT];     // [key][ch]
    alignas(16) __shared__ short Vs[HD*LT];       // [ch][key]  (transposed)
    alignas(16) __shared__ short Ps[4][16*LT];    // per-wave P tile [row][key]

    const int bh = blockIdx.x, qt = blockIdx.y;
    const int tid = threadIdx.x, wave = tid >> 6, lane = tid & 63;
    const int c = lane & 15, g = lane >> 4;
    const size_t base = (size_t)bh * SEQ * HD;
    const short* Q = qbuf + base;
    const short* K = kbuf + base;
    const short* V = vbuf + base;
    const int qrow0 = qt*64 + wave*16;

    s16x8 qf0 = *(const s16x8*)(Q + (size_t)(qrow0 + c)*HD + g*8);
    s16x8 qf1 = *(const s16x8*)(Q + (size_t)(qrow0 + c)*HD + 32 + g*8);

    f32x4 o[4] = {};
    float mrow[4] = {-1e30f, -1e30f, -1e30f, -1e30f};
    float lrow[4] = {0.f, 0.f, 0.f, 0.f};

    const int skey = tid >> 2, soff = (tid & 3) * 16;

    for (int kt = 0; kt < SEQ; kt += KB_T) {
        __syncthreads();
        {   // stage K [key][ch] and V transposed [ch][key]
            const short* ksrc = K + (size_t)(kt + skey)*HD + soff;
            *(s16x8*)&Ks[skey*LT + soff]     = *(const s16x8*)ksrc;
            *(s16x8*)&Ks[skey*LT + soff + 8] = *(const s16x8*)(ksrc + 8);
            const short* vsrc = V + (size_t)(kt + skey)*HD + soff;
            s16x8 v0 = *(const s16x8*)vsrc;
            s16x8 v1 = *(const s16x8*)(vsrc + 8);
            #pragma unroll
            for (int e = 0; e < 8; e++) Vs[(soff + e)*LT + skey]     = v0[e];
            #pragma unroll
            for (int e = 0; e < 8; e++) Vs[(soff + 8 + e)*LT + skey] = v1[e];
        }
        __syncthreads();

        // S = Q K^T  (16x64 per wave)
        f32x4 s[4];
        #pragma unroll
        for (int ct = 0; ct < 4; ct++) {
            s16x8 kf0 = *(const s16x8*)&Ks[(ct*16 + c)*LT + g*8];
            s16x8 kf1 = *(const s16x8*)&Ks[(ct*16 + c)*LT + 32 + g*8];
            f32x4 z = {};
            z = __builtin_amdgcn_mfma_f32_16x16x32_bf16(qf0, kf0, z, 0, 0, 0);
            s[ct] = __builtin_amdgcn_mfma_f32_16x16x32_bf16(qf1, kf1, z, 0, 0, 0);
        }

        // online softmax (row j lives in lanes with same l>>4; cols via l&15)
        float pj[4][4];
        #pragma unroll
        for (int j = 0; j < 4; j++) {
            float rm = fmaxf(fmaxf(s[0][j], s[1][j]), fmaxf(s[2][j], s[3][j]));
            rm = fmaxf(rm, __shfl_xor(rm, 1));
            rm = fmaxf(rm, __shfl_xor(rm, 2));
            rm = fmaxf(rm, __shfl_xor(rm, 4));
            rm = fmaxf(rm, __shfl_xor(rm, 8));
            float mn = fmaxf(mrow[j], rm);
            float corr = __expf(mrow[j] - mn);
            float rs = 0.f;
            #pragma unroll
            for (int ct = 0; ct < 4; ct++) {
                float p = __expf(s[ct][j] - mn);
                pj[ct][j] = p; rs += p;
            }
            rs += __shfl_xor(rs, 1); rs += __shfl_xor(rs, 2);
            rs += __shfl_xor(rs, 4); rs += __shfl_xor(rs, 8);
            lrow[j] = lrow[j]*corr + rs;
            mrow[j] = mn;
            #pragma unroll
            for (int ct = 0; ct < 4; ct++) o[ct][j] *= corr;
        }

        // P -> LDS (per-wave buffer), then read back as A-fragments
        short* pw = &Ps[wave][0];
        #pragma unroll
        for (int j = 0; j < 4; j++)
            #pragma unroll
            for (int ct = 0; ct < 4; ct++)
                pw[(g*4 + j)*LT + ct*16 + c] = f2bf(pj[ct][j]);
        __asm__ volatile("s_waitcnt lgkmcnt(0)" ::: "memory");
        __builtin_amdgcn_sched_barrier(0);
        s16x8 pf0 = *(const s16x8*)&pw[c*LT + g*8];
        s16x8 pf1 = *(const s16x8*)&pw[c*LT + 32 + g*8];

        // O += P V
        #pragma unroll
        for (int ct = 0; ct < 4; ct++) {
            s16x8 vf0 = *(const s16x8*)&Vs[(ct*16 + c)*LT + g*8];
            s16x8 vf1 = *(const s16x8*)&Vs[(ct*16 + c)*LT + 32 + g*8];
            o[ct] = __builtin_amdgcn_mfma_f32_16x16x32_bf16(pf0, vf0, o[ct], 0, 0, 0);
            o[ct] = __builtin_amdgcn_mfma_f32_16x16x32_bf16(pf1, vf1, o[ct], 0, 0, 0);
        }
    }

    // epilogue: out[b*N + n][h*64 + ch] = o / l
    const int b = bh >> 4, h = bh & 15;
    #pragma unroll
    for (int j = 0; j < 4; j++) {
        float inv = 1.0f / lrow[j];
        int nrow = qrow0 + g*4 + j;
        float* dst = aout + ((size_t)(b*SEQ + nrow))*DIM + h*HD;
        #pragma unroll
        for (int ct = 0; ct < 4; ct++) dst[ct*16 + c] = o[ct][j] * inv;
    }
}

// ---------------------------------------------------------------------------
extern "C" void kernel_launch(void* const* d_in, const int* in_sizes, int n_in,
                              void* d_out, int out_size, void* d_ws, size_t ws_size,
                              hipStream_t stream)
{
    const float* x     = (const float*)d_in[0];
    const float* Wqkv  = (const float*)d_in[1];
    const float* qg    = (const float*)d_in[2];
    const float* qbeta = (const float*)d_in[3];
    const float* kg    = (const float*)d_in[4];
    const float* kbeta = (const float*)d_in[5];
    const float* Wproj = (const float*)d_in[6];
    const float* bproj = (const float*)d_in[7];
    float* out = (float*)d_out;

    char* ws = (char*)d_ws;
    const size_t qkv_elems = (size_t)BATCH*HEADS*SEQ*HD;   // 4,194,304
    short* q = (short*)(ws);
    short* k = (short*)(ws + qkv_elems*2);
    short* v = (short*)(ws + qkv_elems*4);
    float* aout = (float*)(ws + qkv_elems*6);              // [ROWS][DIM] fp32

    // 1. QKV GEMM (M=4096, N=3072, K=1024), scatter to q/k/v bf16 [B,H,N,D]
    gemm_kernel<0><<<dim3(3*DIM/BN, ROWS/BM), 256, 0, stream>>>(
        x, Wqkv, nullptr, q, k, v, nullptr);

    // 2. LayerNorm on q (with scale) and k
    ln_qk<<<dim3(2*BATCH*HEADS*SEQ/4), 256, 0, stream>>>(q, k, qg, qbeta, kg, kbeta);

    // 3. Flash attention -> aout fp32 [B*N][DIM]
    attn_kernel<<<dim3(BATCH*HEADS, SEQ/64), 256, 0, stream>>>(q, k, v, aout);

    // 4. Projection GEMM (M=4096, N=1024, K=1024) + bias -> d_out fp32
    gemm_kernel<1><<<dim3(DIM/BN, ROWS/BM), 256, 0, stream>>>(
        aout, Wproj, bproj, nullptr, nullptr, nullptr, out);
}